// Round 7
// baseline (232.451 us; speedup 1.0000x reference)
//
#include <hip/hip_runtime.h>
#include <hip/hip_bf16.h>
#include <stdint.h>

#define V 23
#define VP 24          // v padded with zeros
#define KK 3
#define H 8
#define CG 16          // channels per group (in == out)
#define TDIM 256
#define NB 32
#define TT 64          // t-tile for VALU fallback kernel
#define TTM 32         // t-tile for MFMA kernel (2 row-tiles of 16)
#define OUTC 128
#define CIN 128
#define KDIM 384       // CG*VP contraction length
#define NSTEP 12       // KDIM/32 MFMA k-steps
#define NCT 24         // 384/16 output col tiles (cols = o*24+w)
#define XROW 392       // LDS A-row stride in bf16 elems (784 B = 49*16, 16B aligned)

// ws layout (float offsets):
#define WS_BNA   0                        // [K][H][VP][VP]  (fallback path only)
#define WS_SCALE (KK*H*VP*VP)             // 13824
#define WS_OFFS  (WS_SCALE + OUTC)        // 13952
#define WS_WT    (WS_OFFS + OUTC)         // 14080: Wt[k][h][c][o] (fallback only)
#define WS_MB    (WS_WT + KK*H*CG*CG)     // 20224: Mb bf16 [h][s][ct][lane][8]
#define MB_ELEMS ((size_t)H * NSTEP * NCT * 512)          // bf16 elements
#define WS_NEED_BYTES ((size_t)WS_MB * 4 + MB_ELEMS * 2)  // 2,440,192 B

typedef __attribute__((ext_vector_type(8))) short bf16x8;
typedef __attribute__((ext_vector_type(4))) float f32x4;

static __device__ __forceinline__ uint32_t f2bf_rne(float f) {
  uint32_t u = __float_as_uint(f);
  return (u + 0x7fffu + ((u >> 16) & 1u)) >> 16;
}
static __device__ __forceinline__ float bf2f(uint16_t h) {
  return __uint_as_float(((uint32_t)h) << 16);
}

// ---------------- fused prep (mfma path): ONE dispatch ----------------
__global__ void prep_fused(const float* __restrict__ emb,
                           const float* __restrict__ A,
                           const float* __restrict__ conv_w,
                           const float* __restrict__ conv_b,
                           const float* __restrict__ gamma,
                           const float* __restrict__ beta,
                           const float* __restrict__ mean,
                           const float* __restrict__ var,
                           const int* __restrict__ hop,
                           int n_hop, float* __restrict__ ws) {
  __shared__ int   hopL[V * V];
  __shared__ float AL[KK][V * V];
  __shared__ float eL[KK][32];
  __shared__ float WtL[KK][CG * CG];
  __shared__ float BnT[KK][VP * VP];     // transposed: BnT[k][w*VP+v]
  __shared__ float nbL[KK][V], naL[KK][V];

  const int h = blockIdx.x;
  const int s = blockIdx.y;
  const int tid = threadIdx.x;

  for (int i = tid; i < V * V; i += 256) hopL[i] = hop[i];
  for (int i = tid; i < KK * V * V; i += 256) {
    int k = i / (V * V), r = i % (V * V);
    AL[k][r] = A[((size_t)(k * H + h)) * V * V + r];
  }
  for (int i = tid; i < KK * 32; i += 256) {
    int k = i >> 5, j = i & 31;
    eL[k][j] = (j < n_hop) ? emb[(size_t)(k * H + h) * n_hop + j] : 0.f;
  }
  for (int i = tid; i < KK * CG * CG; i += 256) {
    int o = i & 15, c = (i >> 4) & 15, k = i >> 8;
    WtL[k][c * CG + o] = conv_w[((k * OUTC) + h * CG + o) * CG + c];
  }
  __syncthreads();

  if (tid < KK * V) {
    int k = tid / V, w = tid % V;
    float sb = 0.f, sa = 0.f;
    for (int v = 0; v < V; ++v) {
      float bv = eL[k][hopL[v * V + w]];
      float av = AL[k][v * V + w];
      sb += bv * bv;
      sa += av * av;
    }
    nbL[k][w] = sqrtf(sb) + 1e-4f;
    naL[k][w] = sqrtf(sa) + 1e-4f;
  } else if (s == 0 && tid >= 192 && tid < 192 + CG) {
    int oc = h * CG + (tid - 192);
    float inv = gamma[oc] * rsqrtf(var[oc] + 1e-5f);
    float sb = conv_b[oc] + conv_b[OUTC + oc] + conv_b[2 * OUTC + oc];
    ws[WS_SCALE + oc] = inv;
    ws[WS_OFFS + oc] = beta[oc] - mean[oc] * inv + sb * inv;
  }
  __syncthreads();

  for (int i = tid; i < KK * VP * VP; i += 256) {
    int k = i / (VP * VP), r = i % (VP * VP);
    int w = r / VP, v = r % VP;
    float val = 0.f;
    if (v < V && w < V)
      val = eL[k][hopL[v * V + w]] / nbL[k][w] + AL[k][v * V + w] / naL[k][w];
    BnT[k][w * VP + v] = val;
  }
  __syncthreads();

  uint16_t* mb = (uint16_t*)(ws + WS_MB);
  for (int idx = tid; idx < NCT * 64; idx += 256) {
    int lane = idx & 63, ct = idx >> 6;
    int col = ct * 16 + (lane & 15);
    int o = col / VP, w = col - o * VP;
    int q = lane >> 4;
    int k0 = s * 32 + q * 8;
    int ci = k0 / VP, v0 = k0 - ci * VP;
    float wt0 = WtL[0][ci * CG + o];
    float wt1 = WtL[1][ci * CG + o];
    float wt2 = WtL[2][ci * CG + o];
    const float* b0 = &BnT[0][w * VP + v0];
    const float* b1 = &BnT[1][w * VP + v0];
    const float* b2 = &BnT[2][w * VP + v0];
    uint32_t packed[4];
#pragma unroll
    for (int jj = 0; jj < 4; ++jj) {
      float vlo = 0.f, vhi = 0.f;
      int j0 = jj * 2, j1 = jj * 2 + 1;
      if (w < V) {
        if (v0 + j0 < V) vlo = wt0 * b0[j0] + wt1 * b1[j0] + wt2 * b2[j0];
        if (v0 + j1 < V) vhi = wt0 * b0[j1] + wt1 * b1[j1] + wt2 * b2[j1];
      }
      packed[jj] = f2bf_rne(vlo) | (f2bf_rne(vhi) << 16);
    }
    *(uint4*)&mb[((size_t)(h * NSTEP + s) * NCT + ct) * 512 + lane * 8] =
        make_uint4(packed[0], packed[1], packed[2], packed[3]);
  }
}

// ---------------- prep1 (fallback path only) ----------------
__global__ void prep1_kernel(const float* __restrict__ emb,
                             const float* __restrict__ A,
                             const float* __restrict__ conv_w,
                             const float* __restrict__ conv_b,
                             const float* __restrict__ gamma,
                             const float* __restrict__ beta,
                             const float* __restrict__ mean,
                             const float* __restrict__ var,
                             const int* __restrict__ hop,
                             int n_hop, float* __restrict__ ws) {
  int b = blockIdx.x;
  int tid = threadIdx.x;
  if (b < KK * H) {
    __shared__ float nbv[VP], nav[VP];
    const float* e = emb + b * n_hop;
    const float* a = A + b * V * V;
    if (tid < VP) {
      float nb = 1.f, na = 1.f;
      if (tid < V) {
        float sb = 0.f, sa = 0.f;
        for (int v = 0; v < V; ++v) {
          float bv = e[hop[v * V + tid]];
          float av = a[v * V + tid];
          sb += bv * bv;
          sa += av * av;
        }
        nb = sqrtf(sb) + 1e-4f;
        na = sqrtf(sa) + 1e-4f;
      }
      nbv[tid] = nb;
      nav[tid] = na;
    }
    __syncthreads();
    float* dst = ws + WS_BNA + b * VP * VP;
    for (int idx = tid; idx < VP * VP; idx += 256) {
      int v = idx / VP, w = idx % VP;
      float val = 0.f;
      if (v < V && w < V)
        val = e[hop[v * V + w]] / nbv[w] + a[v * V + w] / nav[w];
      dst[idx] = val;
    }
  } else if (b == KK * H) {
    if (tid < OUTC) {
      float inv = gamma[tid] * rsqrtf(var[tid] + 1e-5f);
      float sb = conv_b[tid] + conv_b[OUTC + tid] + conv_b[2 * OUTC + tid];
      ws[WS_SCALE + tid] = inv;
      ws[WS_OFFS + tid] = beta[tid] - mean[tid] * inv + sb * inv;
    }
  } else {
    int idx = (b - KK * H - 1) * 256 + tid;
    if (idx < KK * H * CG * CG) {
      int o = idx & 15, c = (idx >> 4) & 15, h = (idx >> 8) & 7, k = idx >> 11;
      ws[WS_WT + ((k * H + h) * CG + c) * CG + o] =
          conv_w[((k * OUTC) + h * CG + o) * CG + c];
    }
  }
}

// ---------------- MFMA main ----------------
// R6 register pipeline + (new) h-on-blockIdx.x so each XCD serves ONE h
// (294KB mb slice becomes L2-resident) + LDS-staged coalesced epilogue
// (kills the 2x write amplification seen in R6: WRITE_SIZE 105MB vs 52MB out).
#define LOADB(arr, s_)                                                     \
  {                                                                        \
    _Pragma("unroll")                                                      \
    for (int c6 = 0; c6 < 6; ++c6)                                         \
      arr[c6] = *(const bf16x8*)(mb + (size_t)((s_) * NCT + c6) * 512);    \
  }

#define STEPB(arr, s_)                                                     \
  {                                                                        \
    bf16x8 af[2];                                                          \
    _Pragma("unroll")                                                      \
    for (int rt = 0; rt < 2; ++rt)                                         \
      af[rt] = *(const bf16x8*)&Xa[(rt * 16 + m) * XROW + (s_) * 32 + q * 8]; \
    _Pragma("unroll")                                                      \
    for (int c6 = 0; c6 < 6; ++c6)                                         \
      _Pragma("unroll")                                                    \
      for (int rt = 0; rt < 2; ++rt)                                       \
        acc[rt][c6] = __builtin_amdgcn_mfma_f32_16x16x32_bf16(             \
            af[rt], arr[c6], acc[rt][c6], 0, 0, 0);                        \
  }

__global__ __launch_bounds__(256, 3) void gcn_main_mfma(
    const float* __restrict__ x,
    const float* __restrict__ ws,
    float* __restrict__ out) {
  __shared__ __align__(16) uint16_t Xa[TTM * XROW];   // 25088 B
  __shared__ float Yst[CG][16][VP];                   // 24576 B epilogue stage

  const int tid = threadIdx.x;
  const int h  = blockIdx.x;            // h on bx: XCD = bid%8 = h -> mb L2-res
  const int t0 = blockIdx.y * TTM;
  const int n  = blockIdx.z;

  const int wave = tid >> 6, lane = tid & 63;
  const int m = lane & 15, q = lane >> 4;

  const uint16_t* mb = (const uint16_t*)(ws + WS_MB) +
                       ((size_t)h * NSTEP * NCT + wave * 6) * 512 + lane * 8;

  // prologue: issue first pair of B-step loads; latency hides under x staging
  bf16x8 bA[6], bB[6], bC[6], bD[6];
  LOADB(bA, 0);
  LOADB(bB, 1);

  for (int u = tid; u < CG * TTM * 6; u += 256) {
    int c = u / (TTM * 6);
    int r = u % (TTM * 6);
    int tt = r / 6, vc = r % 6;
    const float* xrow =
        x + ((size_t)((n * CIN + h * CG + c) * TDIM) + (t0 + tt)) * V;
    float f0 = xrow[vc * 4 + 0];
    float f1 = xrow[vc * 4 + 1];
    float f2 = xrow[vc * 4 + 2];
    float f3 = (vc < 5) ? xrow[vc * 4 + 3] : 0.f;
    uint32_t lo = f2bf_rne(f0) | (f2bf_rne(f1) << 16);
    uint32_t hi = f2bf_rne(f2) | (f2bf_rne(f3) << 16);
    *(uint2*)&Xa[tt * XROW + c * VP + vc * 4] = make_uint2(lo, hi);
  }
  __syncthreads();

  f32x4 acc[2][6];
#pragma unroll
  for (int rt = 0; rt < 2; ++rt)
#pragma unroll
    for (int c6 = 0; c6 < 6; ++c6) acc[rt][c6] = (f32x4){0.f, 0.f, 0.f, 0.f};

  // 12 steps, fully unrolled, pair ping-pong register pipeline.
  LOADB(bC, 2);
  LOADB(bD, 3);
  STEPB(bA, 0);
  STEPB(bB, 1);
  LOADB(bA, 4);
  LOADB(bB, 5);
  STEPB(bC, 2);
  STEPB(bD, 3);
  LOADB(bC, 6);
  LOADB(bD, 7);
  STEPB(bA, 4);
  STEPB(bB, 5);
  LOADB(bA, 8);
  LOADB(bB, 9);
  STEPB(bC, 6);
  STEPB(bD, 7);
  LOADB(bC, 10);
  LOADB(bD, 11);
  STEPB(bA, 8);
  STEPB(bB, 9);
  STEPB(bC, 10);
  STEPB(bD, 11);

  // fold BN + residual + relu in-register (reads Xa)
#pragma unroll
  for (int c6 = 0; c6 < 6; ++c6) {
    int col = (wave * 6 + c6) * 16 + m;
    int o = col / VP;
    float sc = ws[WS_SCALE + h * CG + o];
    float of = ws[WS_OFFS + h * CG + o];
#pragma unroll
    for (int rt = 0; rt < 2; ++rt)
#pragma unroll
      for (int reg = 0; reg < 4; ++reg) {
        int row = rt * 16 + q * 4 + reg;
        float resid = bf2f(Xa[row * XROW + col]);
        acc[rt][c6][reg] = fmaxf(fmaf(acc[rt][c6][reg], sc, of) + resid, 0.f);
      }
  }

  // two 16-row chunks: scatter to Yst, then stream out contiguously.
  for (int rtc = 0; rtc < 2; ++rtc) {
    __syncthreads();                     // Yst free for (re)use
#pragma unroll
    for (int c6 = 0; c6 < 6; ++c6) {
      int col = (wave * 6 + c6) * 16 + m;
      int o = col / VP, w = col - o * VP;
      if (w < V) {
#pragma unroll
        for (int reg = 0; reg < 4; ++reg)
          Yst[o][q * 4 + reg][w] = acc[rtc][c6][reg];
      }
    }
    __syncthreads();
    // per o: 16 rows x 23 w = 1472B contiguous; lane-consecutive addresses.
    float* ob = out + ((size_t)(n * OUTC + h * CG) * TDIM + t0 + rtc * 16) * V;
    for (int i = tid; i < CG * 16 * V; i += 256) {
      int o = i / (16 * V), rest = i - o * (16 * V);
      int r = rest / V, w = rest - r * V;
      ob[(size_t)o * TDIM * V + r * V + w] = Yst[o][r][w];
    }
  }
}

// ---------------- fallback VALU main (81 KB ws, round-2 proven) ----------------
__global__ __launch_bounds__(256, 3) void gcn_main_valu(
    const float* __restrict__ x,
    const float* __restrict__ ws,
    float* __restrict__ out) {
  __shared__ __align__(16) uint16_t Xs[CG * TT * VP];

  const int tid = threadIdx.x;
  const int t0 = blockIdx.x * TT;
  const int h  = blockIdx.y;
  const int n  = blockIdx.z;

  for (int u = tid; u < CG * TT * 6; u += 256) {
    int c = u / (TT * 6);
    int r = u % (TT * 6);
    int tt = r / 6, vc = r % 6;
    const float* xrow =
        x + ((size_t)((n * CIN + h * CG + c) * TDIM) + (t0 + tt)) * V;
    float f0 = xrow[vc * 4 + 0];
    float f1 = xrow[vc * 4 + 1];
    float f2 = xrow[vc * 4 + 2];
    float f3 = (vc < 5) ? xrow[vc * 4 + 3] : 0.f;
    uint32_t lo = f2bf_rne(f0) | (f2bf_rne(f1) << 16);
    uint32_t hi = f2bf_rne(f2) | (f2bf_rne(f3) << 16);
    *(uint2*)&Xs[(c * TT + tt) * VP + vc * 4] = make_uint2(lo, hi);
  }
  __syncthreads();

  const int oq = __builtin_amdgcn_readfirstlane(tid >> 6);
  const int tt = tid & 63;

  const float* wt  = ws + WS_WT  + ((size_t)h * CG * CG);
  const float* bna = ws + WS_BNA + ((size_t)h * VP * VP);

  float acc[4][VP];
#pragma unroll
  for (int o = 0; o < 4; ++o)
#pragma unroll
    for (int w = 0; w < VP; ++w) acc[o][w] = 0.f;

  for (int k = 0; k < KK; ++k) {
    const float* wtk  = wt  + (size_t)k * H * CG * CG;
    const float* bnak = bna + (size_t)k * H * VP * VP;
    for (int vb = 0; vb < 3; ++vb) {
      float xwv[4][8];
#pragma unroll
      for (int o = 0; o < 4; ++o)
#pragma unroll
        for (int j = 0; j < 8; ++j) xwv[o][j] = 0.f;
#pragma unroll 4
      for (int c = 0; c < CG; ++c) {
        uint4 raw = *(const uint4*)&Xs[(c * TT + tt) * VP + vb * 8];
        float4 wv = *(const float4*)&wtk[c * CG + (oq << 2)];
        float xv[8];
        xv[0] = __uint_as_float(raw.x << 16);
        xv[1] = __uint_as_float(raw.x & 0xffff0000u);
        xv[2] = __uint_as_float(raw.y << 16);
        xv[3] = __uint_as_float(raw.y & 0xffff0000u);
        xv[4] = __uint_as_float(raw.z << 16);
        xv[5] = __uint_as_float(raw.z & 0xffff0000u);
        xv[6] = __uint_as_float(raw.w << 16);
        xv[7] = __uint_as_float(raw.w & 0xffff0000u);
#pragma unroll
        for (int o = 0; o < 4; ++o) {
          float wo = (&wv.x)[o];
#pragma unroll
          for (int j = 0; j < 8; ++j) xwv[o][j] = fmaf(wo, xv[j], xwv[o][j]);
        }
      }
#pragma unroll
      for (int j = 0; j < 8; ++j) {
        const int v = vb * 8 + j;
        const float* bnrow = &bnak[v * VP];
#pragma unroll
        for (int wb = 0; wb < 6; ++wb) {
          float4 bn = *(const float4*)(bnrow + wb * 4);
#pragma unroll
          for (int o = 0; o < 4; ++o) {
            acc[o][wb * 4 + 0] = fmaf(xwv[o][j], bn.x, acc[o][wb * 4 + 0]);
            acc[o][wb * 4 + 1] = fmaf(xwv[o][j], bn.y, acc[o][wb * 4 + 1]);
            acc[o][wb * 4 + 2] = fmaf(xwv[o][j], bn.z, acc[o][wb * 4 + 2]);
            acc[o][wb * 4 + 3] = fmaf(xwv[o][j], bn.w, acc[o][wb * 4 + 3]);
          }
        }
      }
    }
  }

#pragma unroll
  for (int o = 0; o < 4; ++o) {
    int og = (oq << 2) + o;
    int oc = h * CG + og;
    float sc = ws[WS_SCALE + oc];
    float of = ws[WS_OFFS + oc];
    float* orow = out + ((size_t)(n * OUTC + oc) * TDIM + (t0 + tt)) * V;
    const uint16_t* xsrow = &Xs[(og * TT + tt) * VP];
#pragma unroll
    for (int w = 0; w < V; ++w) {
      float resid = bf2f(xsrow[w]);
      float y = fmaf(acc[o][w], sc, of) + resid;
      orow[w] = fmaxf(y, 0.f);
    }
  }
}

extern "C" void kernel_launch(void* const* d_in, const int* in_sizes, int n_in,
                              void* d_out, int out_size, void* d_ws, size_t ws_size,
                              hipStream_t stream) {
  const float* x      = (const float*)d_in[0];
  const float* emb    = (const float*)d_in[1];
  const float* A      = (const float*)d_in[2];
  const float* conv_w = (const float*)d_in[3];
  const float* conv_b = (const float*)d_in[4];
  const float* gamma  = (const float*)d_in[5];
  const float* beta   = (const float*)d_in[6];
  const float* mean   = (const float*)d_in[7];
  const float* var    = (const float*)d_in[8];
  const int*   hop    = (const int*)d_in[9];
  float* ws  = (float*)d_ws;
  float* out = (float*)d_out;

  int n_hop = in_sizes[1] / (KK * H);

  if (ws_size >= WS_NEED_BYTES) {
    prep_fused<<<dim3(H, NSTEP), dim3(256), 0, stream>>>(
        emb, A, conv_w, conv_b, gamma, beta, mean, var, hop, n_hop, ws);
    gcn_main_mfma<<<dim3(H, TDIM / TTM, NB), dim3(256), 0, stream>>>(x, ws, out);
  } else {
    prep1_kernel<<<dim3(KK * H + 1 + 24), dim3(256), 0, stream>>>(
        emb, A, conv_w, conv_b, gamma, beta, mean, var, hop, n_hop, ws);
    gcn_main_valu<<<dim3(TDIM / TT, H, NB), dim3(256), 0, stream>>>(x, ws, out);
  }
}

// Round 8
// 225.179 us; speedup vs baseline: 1.0323x; 1.0323x over previous
//
#include <hip/hip_runtime.h>
#include <hip/hip_bf16.h>
#include <stdint.h>

#define V 23
#define VP 24          // v padded with zeros
#define KK 3
#define H 8
#define CG 16          // channels per group (in == out)
#define TDIM 256
#define NB 32
#define TT 64          // t-tile for VALU fallback kernel
#define TTM 32         // t-tile for MFMA kernel (2 row-tiles of 16)
#define OUTC 128
#define CIN 128
#define KDIM 384       // CG*VP contraction length
#define NSTEP 12       // KDIM/32 MFMA k-steps
#define NCT 24         // 384/16 output col tiles (cols = o*24+w)
#define XROW 392       // LDS A-row stride in bf16 elems (784 B = 49*16, 16B aligned)

// ws layout (float offsets):
#define WS_BNA   0                        // [K][H][VP][VP]  (fallback path only)
#define WS_SCALE (KK*H*VP*VP)             // 13824
#define WS_OFFS  (WS_SCALE + OUTC)        // 13952
#define WS_WT    (WS_OFFS + OUTC)         // 14080: Wt[k][h][c][o] (fallback only)
#define WS_MB    (WS_WT + KK*H*CG*CG)     // 20224: Mb bf16 [h][s][ct][lane][8]
#define MB_ELEMS ((size_t)H * NSTEP * NCT * 512)          // bf16 elements
#define WS_NEED_BYTES ((size_t)WS_MB * 4 + MB_ELEMS * 2)  // 2,440,192 B

typedef __attribute__((ext_vector_type(8))) short bf16x8;
typedef __attribute__((ext_vector_type(4))) float f32x4;

static __device__ __forceinline__ uint32_t f2bf_rne(float f) {
  uint32_t u = __float_as_uint(f);
  return (u + 0x7fffu + ((u >> 16) & 1u)) >> 16;
}
static __device__ __forceinline__ float bf2f(uint16_t h) {
  return __uint_as_float(((uint32_t)h) << 16);
}

// ---------------- fused prep (mfma path): ONE dispatch ----------------
__global__ void prep_fused(const float* __restrict__ emb,
                           const float* __restrict__ A,
                           const float* __restrict__ conv_w,
                           const float* __restrict__ conv_b,
                           const float* __restrict__ gamma,
                           const float* __restrict__ beta,
                           const float* __restrict__ mean,
                           const float* __restrict__ var,
                           const int* __restrict__ hop,
                           int n_hop, float* __restrict__ ws) {
  __shared__ int   hopL[V * V];
  __shared__ float AL[KK][V * V];
  __shared__ float eL[KK][32];
  __shared__ float WtL[KK][CG * CG];
  __shared__ float BnT[KK][VP * VP];     // transposed: BnT[k][w*VP+v]
  __shared__ float nbL[KK][V], naL[KK][V];

  const int h = blockIdx.x;
  const int s = blockIdx.y;
  const int tid = threadIdx.x;

  for (int i = tid; i < V * V; i += 256) hopL[i] = hop[i];
  for (int i = tid; i < KK * V * V; i += 256) {
    int k = i / (V * V), r = i % (V * V);
    AL[k][r] = A[((size_t)(k * H + h)) * V * V + r];
  }
  for (int i = tid; i < KK * 32; i += 256) {
    int k = i >> 5, j = i & 31;
    eL[k][j] = (j < n_hop) ? emb[(size_t)(k * H + h) * n_hop + j] : 0.f;
  }
  for (int i = tid; i < KK * CG * CG; i += 256) {
    int o = i & 15, c = (i >> 4) & 15, k = i >> 8;
    WtL[k][c * CG + o] = conv_w[((k * OUTC) + h * CG + o) * CG + c];
  }
  __syncthreads();

  if (tid < KK * V) {
    int k = tid / V, w = tid % V;
    float sb = 0.f, sa = 0.f;
    for (int v = 0; v < V; ++v) {
      float bv = eL[k][hopL[v * V + w]];
      float av = AL[k][v * V + w];
      sb += bv * bv;
      sa += av * av;
    }
    nbL[k][w] = sqrtf(sb) + 1e-4f;
    naL[k][w] = sqrtf(sa) + 1e-4f;
  } else if (s == 0 && tid >= 192 && tid < 192 + CG) {
    int oc = h * CG + (tid - 192);
    float inv = gamma[oc] * rsqrtf(var[oc] + 1e-5f);
    float sb = conv_b[oc] + conv_b[OUTC + oc] + conv_b[2 * OUTC + oc];
    ws[WS_SCALE + oc] = inv;
    ws[WS_OFFS + oc] = beta[oc] - mean[oc] * inv + sb * inv;
  }
  __syncthreads();

  for (int i = tid; i < KK * VP * VP; i += 256) {
    int k = i / (VP * VP), r = i % (VP * VP);
    int w = r / VP, v = r % VP;
    float val = 0.f;
    if (v < V && w < V)
      val = eL[k][hopL[v * V + w]] / nbL[k][w] + AL[k][v * V + w] / naL[k][w];
    BnT[k][w * VP + v] = val;
  }
  __syncthreads();

  uint16_t* mb = (uint16_t*)(ws + WS_MB);
  for (int idx = tid; idx < NCT * 64; idx += 256) {
    int lane = idx & 63, ct = idx >> 6;
    int col = ct * 16 + (lane & 15);
    int o = col / VP, w = col - o * VP;
    int q = lane >> 4;
    int k0 = s * 32 + q * 8;
    int ci = k0 / VP, v0 = k0 - ci * VP;
    float wt0 = WtL[0][ci * CG + o];
    float wt1 = WtL[1][ci * CG + o];
    float wt2 = WtL[2][ci * CG + o];
    const float* b0 = &BnT[0][w * VP + v0];
    const float* b1 = &BnT[1][w * VP + v0];
    const float* b2 = &BnT[2][w * VP + v0];
    uint32_t packed[4];
#pragma unroll
    for (int jj = 0; jj < 4; ++jj) {
      float vlo = 0.f, vhi = 0.f;
      int j0 = jj * 2, j1 = jj * 2 + 1;
      if (w < V) {
        if (v0 + j0 < V) vlo = wt0 * b0[j0] + wt1 * b1[j0] + wt2 * b2[j0];
        if (v0 + j1 < V) vhi = wt0 * b0[j1] + wt1 * b1[j1] + wt2 * b2[j1];
      }
      packed[jj] = f2bf_rne(vlo) | (f2bf_rne(vhi) << 16);
    }
    *(uint4*)&mb[((size_t)(h * NSTEP + s) * NCT + ct) * 512 + lane * 8] =
        make_uint4(packed[0], packed[1], packed[2], packed[3]);
  }
}

// ---------------- prep1 (fallback path only) ----------------
__global__ void prep1_kernel(const float* __restrict__ emb,
                             const float* __restrict__ A,
                             const float* __restrict__ conv_w,
                             const float* __restrict__ conv_b,
                             const float* __restrict__ gamma,
                             const float* __restrict__ beta,
                             const float* __restrict__ mean,
                             const float* __restrict__ var,
                             const int* __restrict__ hop,
                             int n_hop, float* __restrict__ ws) {
  int b = blockIdx.x;
  int tid = threadIdx.x;
  if (b < KK * H) {
    __shared__ float nbv[VP], nav[VP];
    const float* e = emb + b * n_hop;
    const float* a = A + b * V * V;
    if (tid < VP) {
      float nb = 1.f, na = 1.f;
      if (tid < V) {
        float sb = 0.f, sa = 0.f;
        for (int v = 0; v < V; ++v) {
          float bv = e[hop[v * V + tid]];
          float av = a[v * V + tid];
          sb += bv * bv;
          sa += av * av;
        }
        nb = sqrtf(sb) + 1e-4f;
        na = sqrtf(sa) + 1e-4f;
      }
      nbv[tid] = nb;
      nav[tid] = na;
    }
    __syncthreads();
    float* dst = ws + WS_BNA + b * VP * VP;
    for (int idx = tid; idx < VP * VP; idx += 256) {
      int v = idx / VP, w = idx % VP;
      float val = 0.f;
      if (v < V && w < V)
        val = e[hop[v * V + w]] / nbv[w] + a[v * V + w] / nav[w];
      dst[idx] = val;
    }
  } else if (b == KK * H) {
    if (tid < OUTC) {
      float inv = gamma[tid] * rsqrtf(var[tid] + 1e-5f);
      float sb = conv_b[tid] + conv_b[OUTC + tid] + conv_b[2 * OUTC + tid];
      ws[WS_SCALE + tid] = inv;
      ws[WS_OFFS + tid] = beta[tid] - mean[tid] * inv + sb * inv;
    }
  } else {
    int idx = (b - KK * H - 1) * 256 + tid;
    if (idx < KK * H * CG * CG) {
      int o = idx & 15, c = (idx >> 4) & 15, h = (idx >> 8) & 7, k = idx >> 11;
      ws[WS_WT + ((k * H + h) * CG + c) * CG + o] =
          conv_w[((k * OUTC) + h * CG + o) * CG + c];
    }
  }
}

// ---------------- MFMA main ----------------
// Exact R6 structure (register pipeline + direct-store epilogue, 83.5us)
// + ONLY change: h on blockIdx.x so XCD = flat_bid%8 = h -> each XCD's
// 294KB mb slice is L2-resident (R7 proved FETCH 65.7->50.6MB; R7's
// regression was the LDS epilogue, reverted here).
#define LOADB(arr, s_)                                                     \
  {                                                                        \
    _Pragma("unroll")                                                      \
    for (int c6 = 0; c6 < 6; ++c6)                                         \
      arr[c6] = *(const bf16x8*)(mb + (size_t)((s_) * NCT + c6) * 512);    \
  }

#define STEPB(arr, s_)                                                     \
  {                                                                        \
    bf16x8 af[2];                                                          \
    _Pragma("unroll")                                                      \
    for (int rt = 0; rt < 2; ++rt)                                         \
      af[rt] = *(const bf16x8*)&Xa[(rt * 16 + m) * XROW + (s_) * 32 + q * 8]; \
    _Pragma("unroll")                                                      \
    for (int c6 = 0; c6 < 6; ++c6)                                         \
      _Pragma("unroll")                                                    \
      for (int rt = 0; rt < 2; ++rt)                                       \
        acc[rt][c6] = __builtin_amdgcn_mfma_f32_16x16x32_bf16(             \
            af[rt], arr[c6], acc[rt][c6], 0, 0, 0);                        \
  }

__global__ __launch_bounds__(256, 3) void gcn_main_mfma(
    const float* __restrict__ x,
    const float* __restrict__ ws,
    float* __restrict__ out) {
  __shared__ __align__(16) uint16_t Xa[TTM * XROW];  // 25088 B

  const int tid = threadIdx.x;
  const int h  = blockIdx.x;            // h pinned to XCD (bid%8 == h)
  const int t0 = blockIdx.y * TTM;
  const int n  = blockIdx.z;

  const int wave = tid >> 6, lane = tid & 63;
  const int m = lane & 15, q = lane >> 4;

  const uint16_t* mb = (const uint16_t*)(ws + WS_MB) +
                       ((size_t)h * NSTEP * NCT + wave * 6) * 512 + lane * 8;

  // prologue: issue first pair of B-step loads; latency hides under x staging
  bf16x8 bA[6], bB[6], bC[6], bD[6];
  LOADB(bA, 0);
  LOADB(bB, 1);

  for (int u = tid; u < CG * TTM * 6; u += 256) {
    int c = u / (TTM * 6);
    int r = u % (TTM * 6);
    int tt = r / 6, vc = r % 6;
    const float* xrow =
        x + ((size_t)((n * CIN + h * CG + c) * TDIM) + (t0 + tt)) * V;
    float f0 = xrow[vc * 4 + 0];
    float f1 = xrow[vc * 4 + 1];
    float f2 = xrow[vc * 4 + 2];
    float f3 = (vc < 5) ? xrow[vc * 4 + 3] : 0.f;
    uint32_t lo = f2bf_rne(f0) | (f2bf_rne(f1) << 16);
    uint32_t hi = f2bf_rne(f2) | (f2bf_rne(f3) << 16);
    *(uint2*)&Xa[tt * XROW + c * VP + vc * 4] = make_uint2(lo, hi);
  }
  __syncthreads();

  f32x4 acc[2][6];
#pragma unroll
  for (int rt = 0; rt < 2; ++rt)
#pragma unroll
    for (int c6 = 0; c6 < 6; ++c6) acc[rt][c6] = (f32x4){0.f, 0.f, 0.f, 0.f};

  // 12 steps, fully unrolled, pair ping-pong register pipeline.
  LOADB(bC, 2);
  LOADB(bD, 3);
  STEPB(bA, 0);
  STEPB(bB, 1);
  LOADB(bA, 4);
  LOADB(bB, 5);
  STEPB(bC, 2);
  STEPB(bD, 3);
  LOADB(bC, 6);
  LOADB(bD, 7);
  STEPB(bA, 4);
  STEPB(bB, 5);
  LOADB(bA, 8);
  LOADB(bB, 9);
  STEPB(bC, 6);
  STEPB(bD, 7);
  LOADB(bC, 10);
  LOADB(bD, 11);
  STEPB(bA, 8);
  STEPB(bB, 9);
  STEPB(bC, 10);
  STEPB(bD, 11);

#pragma unroll
  for (int c6 = 0; c6 < 6; ++c6) {
    int col = (wave * 6 + c6) * 16 + m;
    int o = col / VP, w = col - o * VP;
    float sc = ws[WS_SCALE + h * CG + o];
    float of = ws[WS_OFFS + h * CG + o];
    bool valid = (w < V);
    float* obase =
        out + ((size_t)(n * OUTC + h * CG + o) * TDIM + t0) * V + w;
#pragma unroll
    for (int rt = 0; rt < 2; ++rt) {
#pragma unroll
      for (int reg = 0; reg < 4; ++reg) {
        int row = rt * 16 + q * 4 + reg;
        float resid = bf2f(Xa[row * XROW + col]);
        float y = fmaf(acc[rt][c6][reg], sc, of) + resid;
        if (valid) obase[(size_t)row * V] = fmaxf(y, 0.f);
      }
    }
  }
}

// ---------------- fallback VALU main (81 KB ws, round-2 proven) ----------------
__global__ __launch_bounds__(256, 3) void gcn_main_valu(
    const float* __restrict__ x,
    const float* __restrict__ ws,
    float* __restrict__ out) {
  __shared__ __align__(16) uint16_t Xs[CG * TT * VP];

  const int tid = threadIdx.x;
  const int t0 = blockIdx.x * TT;
  const int h  = blockIdx.y;
  const int n  = blockIdx.z;

  for (int u = tid; u < CG * TT * 6; u += 256) {
    int c = u / (TT * 6);
    int r = u % (TT * 6);
    int tt = r / 6, vc = r % 6;
    const float* xrow =
        x + ((size_t)((n * CIN + h * CG + c) * TDIM) + (t0 + tt)) * V;
    float f0 = xrow[vc * 4 + 0];
    float f1 = xrow[vc * 4 + 1];
    float f2 = xrow[vc * 4 + 2];
    float f3 = (vc < 5) ? xrow[vc * 4 + 3] : 0.f;
    uint32_t lo = f2bf_rne(f0) | (f2bf_rne(f1) << 16);
    uint32_t hi = f2bf_rne(f2) | (f2bf_rne(f3) << 16);
    *(uint2*)&Xs[(c * TT + tt) * VP + vc * 4] = make_uint2(lo, hi);
  }
  __syncthreads();

  const int oq = __builtin_amdgcn_readfirstlane(tid >> 6);
  const int tt = tid & 63;

  const float* wt  = ws + WS_WT  + ((size_t)h * CG * CG);
  const float* bna = ws + WS_BNA + ((size_t)h * VP * VP);

  float acc[4][VP];
#pragma unroll
  for (int o = 0; o < 4; ++o)
#pragma unroll
    for (int w = 0; w < VP; ++w) acc[o][w] = 0.f;

  for (int k = 0; k < KK; ++k) {
    const float* wtk  = wt  + (size_t)k * H * CG * CG;
    const float* bnak = bna + (size_t)k * H * VP * VP;
    for (int vb = 0; vb < 3; ++vb) {
      float xwv[4][8];
#pragma unroll
      for (int o = 0; o < 4; ++o)
#pragma unroll
        for (int j = 0; j < 8; ++j) xwv[o][j] = 0.f;
#pragma unroll 4
      for (int c = 0; c < CG; ++c) {
        uint4 raw = *(const uint4*)&Xs[(c * TT + tt) * VP + vb * 8];
        float4 wv = *(const float4*)&wtk[c * CG + (oq << 2)];
        float xv[8];
        xv[0] = __uint_as_float(raw.x << 16);
        xv[1] = __uint_as_float(raw.x & 0xffff0000u);
        xv[2] = __uint_as_float(raw.y << 16);
        xv[3] = __uint_as_float(raw.y & 0xffff0000u);
        xv[4] = __uint_as_float(raw.z << 16);
        xv[5] = __uint_as_float(raw.z & 0xffff0000u);
        xv[6] = __uint_as_float(raw.w << 16);
        xv[7] = __uint_as_float(raw.w & 0xffff0000u);
#pragma unroll
        for (int o = 0; o < 4; ++o) {
          float wo = (&wv.x)[o];
#pragma unroll
          for (int j = 0; j < 8; ++j) xwv[o][j] = fmaf(wo, xv[j], xwv[o][j]);
        }
      }
#pragma unroll
      for (int j = 0; j < 8; ++j) {
        const int v = vb * 8 + j;
        const float* bnrow = &bnak[v * VP];
#pragma unroll
        for (int wb = 0; wb < 6; ++wb) {
          float4 bn = *(const float4*)(bnrow + wb * 4);
#pragma unroll
          for (int o = 0; o < 4; ++o) {
            acc[o][wb * 4 + 0] = fmaf(xwv[o][j], bn.x, acc[o][wb * 4 + 0]);
            acc[o][wb * 4 + 1] = fmaf(xwv[o][j], bn.y, acc[o][wb * 4 + 1]);
            acc[o][wb * 4 + 2] = fmaf(xwv[o][j], bn.z, acc[o][wb * 4 + 2]);
            acc[o][wb * 4 + 3] = fmaf(xwv[o][j], bn.w, acc[o][wb * 4 + 3]);
          }
        }
      }
    }
  }

#pragma unroll
  for (int o = 0; o < 4; ++o) {
    int og = (oq << 2) + o;
    int oc = h * CG + og;
    float sc = ws[WS_SCALE + oc];
    float of = ws[WS_OFFS + oc];
    float* orow = out + ((size_t)(n * OUTC + oc) * TDIM + (t0 + tt)) * V;
    const uint16_t* xsrow = &Xs[(og * TT + tt) * VP];
#pragma unroll
    for (int w = 0; w < V; ++w) {
      float resid = bf2f(xsrow[w]);
      float y = fmaf(acc[o][w], sc, of) + resid;
      orow[w] = fmaxf(y, 0.f);
    }
  }
}

extern "C" void kernel_launch(void* const* d_in, const int* in_sizes, int n_in,
                              void* d_out, int out_size, void* d_ws, size_t ws_size,
                              hipStream_t stream) {
  const float* x      = (const float*)d_in[0];
  const float* emb    = (const float*)d_in[1];
  const float* A      = (const float*)d_in[2];
  const float* conv_w = (const float*)d_in[3];
  const float* conv_b = (const float*)d_in[4];
  const float* gamma  = (const float*)d_in[5];
  const float* beta   = (const float*)d_in[6];
  const float* mean   = (const float*)d_in[7];
  const float* var    = (const float*)d_in[8];
  const int*   hop    = (const int*)d_in[9];
  float* ws  = (float*)d_ws;
  float* out = (float*)d_out;

  int n_hop = in_sizes[1] / (KK * H);

  if (ws_size >= WS_NEED_BYTES) {
    prep_fused<<<dim3(H, NSTEP), dim3(256), 0, stream>>>(
        emb, A, conv_w, conv_b, gamma, beta, mean, var, hop, n_hop, ws);
    gcn_main_mfma<<<dim3(H, TDIM / TTM, NB), dim3(256), 0, stream>>>(x, ws, out);
  } else {
    prep1_kernel<<<dim3(KK * H + 1 + 24), dim3(256), 0, stream>>>(
        emb, A, conv_w, conv_b, gamma, beta, mean, var, hop, n_hop, ws);
    gcn_main_valu<<<dim3(TDIM / TT, H, NB), dim3(256), 0, stream>>>(x, ws, out);
  }
}

// Round 9
// 222.027 us; speedup vs baseline: 1.0469x; 1.0142x over previous
//
#include <hip/hip_runtime.h>
#include <hip/hip_bf16.h>
#include <stdint.h>

#define V 23
#define VP 24          // v padded with zeros
#define KK 3
#define H 8
#define CG 16          // channels per group (in == out)
#define TDIM 256
#define NB 32
#define TT 64          // t-tile for VALU fallback kernel
#define TTW 64         // t-tile for MFMA kernel (4 row-tiles of 16, 8 waves)
#define OUTC 128
#define CIN 128
#define KDIM 384       // CG*VP contraction length
#define NSTEP 12       // KDIM/32 MFMA k-steps
#define NCT 24         // 384/16 output col tiles (cols = o*24+w)
#define XROW 392       // LDS A-row stride in bf16 elems (784 B = 49*16, 16B aligned)

// ws layout (float offsets):
#define WS_BNA   0                        // [K][H][VP][VP]  (fallback path only)
#define WS_SCALE (KK*H*VP*VP)             // 13824
#define WS_OFFS  (WS_SCALE + OUTC)        // 13952
#define WS_WT    (WS_OFFS + OUTC)         // 14080: Wt[k][h][c][o] (fallback only)
#define WS_MB    (WS_WT + KK*H*CG*CG)     // 20224: Mb bf16 [h][s][ct][lane][8]
#define MB_ELEMS ((size_t)H * NSTEP * NCT * 512)          // bf16 elements
#define WS_NEED_BYTES ((size_t)WS_MB * 4 + MB_ELEMS * 2)  // 2,440,192 B

typedef __attribute__((ext_vector_type(8))) short bf16x8;
typedef __attribute__((ext_vector_type(4))) float f32x4;

static __device__ __forceinline__ uint32_t f2bf_rne(float f) {
  uint32_t u = __float_as_uint(f);
  return (u + 0x7fffu + ((u >> 16) & 1u)) >> 16;
}
static __device__ __forceinline__ float bf2f(uint16_t h) {
  return __uint_as_float(((uint32_t)h) << 16);
}

// ---------------- fused prep (mfma path): ONE dispatch ----------------
__global__ void prep_fused(const float* __restrict__ emb,
                           const float* __restrict__ A,
                           const float* __restrict__ conv_w,
                           const float* __restrict__ conv_b,
                           const float* __restrict__ gamma,
                           const float* __restrict__ beta,
                           const float* __restrict__ mean,
                           const float* __restrict__ var,
                           const int* __restrict__ hop,
                           int n_hop, float* __restrict__ ws) {
  __shared__ int   hopL[V * V];
  __shared__ float AL[KK][V * V];
  __shared__ float eL[KK][32];
  __shared__ float WtL[KK][CG * CG];
  __shared__ float BnT[KK][VP * VP];     // transposed: BnT[k][w*VP+v]
  __shared__ float nbL[KK][V], naL[KK][V];

  const int h = blockIdx.x;
  const int s = blockIdx.y;
  const int tid = threadIdx.x;

  for (int i = tid; i < V * V; i += 256) hopL[i] = hop[i];
  for (int i = tid; i < KK * V * V; i += 256) {
    int k = i / (V * V), r = i % (V * V);
    AL[k][r] = A[((size_t)(k * H + h)) * V * V + r];
  }
  for (int i = tid; i < KK * 32; i += 256) {
    int k = i >> 5, j = i & 31;
    eL[k][j] = (j < n_hop) ? emb[(size_t)(k * H + h) * n_hop + j] : 0.f;
  }
  for (int i = tid; i < KK * CG * CG; i += 256) {
    int o = i & 15, c = (i >> 4) & 15, k = i >> 8;
    WtL[k][c * CG + o] = conv_w[((k * OUTC) + h * CG + o) * CG + c];
  }
  __syncthreads();

  if (tid < KK * V) {
    int k = tid / V, w = tid % V;
    float sb = 0.f, sa = 0.f;
    for (int v = 0; v < V; ++v) {
      float bv = eL[k][hopL[v * V + w]];
      float av = AL[k][v * V + w];
      sb += bv * bv;
      sa += av * av;
    }
    nbL[k][w] = sqrtf(sb) + 1e-4f;
    naL[k][w] = sqrtf(sa) + 1e-4f;
  } else if (s == 0 && tid >= 192 && tid < 192 + CG) {
    int oc = h * CG + (tid - 192);
    float inv = gamma[oc] * rsqrtf(var[oc] + 1e-5f);
    float sb = conv_b[oc] + conv_b[OUTC + oc] + conv_b[2 * OUTC + oc];
    ws[WS_SCALE + oc] = inv;
    ws[WS_OFFS + oc] = beta[oc] - mean[oc] * inv + sb * inv;
  }
  __syncthreads();

  for (int i = tid; i < KK * VP * VP; i += 256) {
    int k = i / (VP * VP), r = i % (VP * VP);
    int w = r / VP, v = r % VP;
    float val = 0.f;
    if (v < V && w < V)
      val = eL[k][hopL[v * V + w]] / nbL[k][w] + AL[k][v * V + w] / naL[k][w];
    BnT[k][w * VP + v] = val;
  }
  __syncthreads();

  uint16_t* mb = (uint16_t*)(ws + WS_MB);
  for (int idx = tid; idx < NCT * 64; idx += 256) {
    int lane = idx & 63, ct = idx >> 6;
    int col = ct * 16 + (lane & 15);
    int o = col / VP, w = col - o * VP;
    int q = lane >> 4;
    int k0 = s * 32 + q * 8;
    int ci = k0 / VP, v0 = k0 - ci * VP;
    float wt0 = WtL[0][ci * CG + o];
    float wt1 = WtL[1][ci * CG + o];
    float wt2 = WtL[2][ci * CG + o];
    const float* b0 = &BnT[0][w * VP + v0];
    const float* b1 = &BnT[1][w * VP + v0];
    const float* b2 = &BnT[2][w * VP + v0];
    uint32_t packed[4];
#pragma unroll
    for (int jj = 0; jj < 4; ++jj) {
      float vlo = 0.f, vhi = 0.f;
      int j0 = jj * 2, j1 = jj * 2 + 1;
      if (w < V) {
        if (v0 + j0 < V) vlo = wt0 * b0[j0] + wt1 * b1[j0] + wt2 * b2[j0];
        if (v0 + j1 < V) vhi = wt0 * b0[j1] + wt1 * b1[j1] + wt2 * b2[j1];
      }
      packed[jj] = f2bf_rne(vlo) | (f2bf_rne(vhi) << 16);
    }
    *(uint4*)&mb[((size_t)(h * NSTEP + s) * NCT + ct) * 512 + lane * 8] =
        make_uint4(packed[0], packed[1], packed[2], packed[3]);
  }
}

// ---------------- prep1 (fallback path only) ----------------
__global__ void prep1_kernel(const float* __restrict__ emb,
                             const float* __restrict__ A,
                             const float* __restrict__ conv_w,
                             const float* __restrict__ conv_b,
                             const float* __restrict__ gamma,
                             const float* __restrict__ beta,
                             const float* __restrict__ mean,
                             const float* __restrict__ var,
                             const int* __restrict__ hop,
                             int n_hop, float* __restrict__ ws) {
  int b = blockIdx.x;
  int tid = threadIdx.x;
  if (b < KK * H) {
    __shared__ float nbv[VP], nav[VP];
    const float* e = emb + b * n_hop;
    const float* a = A + b * V * V;
    if (tid < VP) {
      float nb = 1.f, na = 1.f;
      if (tid < V) {
        float sb = 0.f, sa = 0.f;
        for (int v = 0; v < V; ++v) {
          float bv = e[hop[v * V + tid]];
          float av = a[v * V + tid];
          sb += bv * bv;
          sa += av * av;
        }
        nb = sqrtf(sb) + 1e-4f;
        na = sqrtf(sa) + 1e-4f;
      }
      nbv[tid] = nb;
      nav[tid] = na;
    }
    __syncthreads();
    float* dst = ws + WS_BNA + b * VP * VP;
    for (int idx = tid; idx < VP * VP; idx += 256) {
      int v = idx / VP, w = idx % VP;
      float val = 0.f;
      if (v < V && w < V)
        val = e[hop[v * V + w]] / nbv[w] + a[v * V + w] / nav[w];
      dst[idx] = val;
    }
  } else if (b == KK * H) {
    if (tid < OUTC) {
      float inv = gamma[tid] * rsqrtf(var[tid] + 1e-5f);
      float sb = conv_b[tid] + conv_b[OUTC + tid] + conv_b[2 * OUTC + tid];
      ws[WS_SCALE + tid] = inv;
      ws[WS_OFFS + tid] = beta[tid] - mean[tid] * inv + sb * inv;
    }
  } else {
    int idx = (b - KK * H - 1) * 256 + tid;
    if (idx < KK * H * CG * CG) {
      int o = idx & 15, c = (idx >> 4) & 15, h = (idx >> 8) & 7, k = idx >> 11;
      ws[WS_WT + ((k * H + h) * CG + c) * CG + o] =
          conv_w[((k * OUTC) + h * CG + o) * CG + c];
    }
  }
}

// ---------------- MFMA main ----------------
// TTW=64 t-rows per block, 8 waves (512 thr): wave=(rp,cs), rp=row-half,
// cs=6-col-tile sextet. Same per-wave reg layout (acc[2][6] + 4-buffer
// pipeline) as the proven 83.5us kernel, but each mb tile now feeds 64
// rows -> mb re-read traffic halves (590->295MB). h pinned to XCD (R8:
// FETCH 65.7->49.5MB). rp-pair waves load identical mb addrs (L1 dedupe).
#define LOADB(arr, s_)                                                     \
  {                                                                        \
    _Pragma("unroll")                                                      \
    for (int c6 = 0; c6 < 6; ++c6)                                         \
      arr[c6] = *(const bf16x8*)(mb + (size_t)((s_) * NCT + c6) * 512);    \
  }

#define STEPB(arr, s_)                                                     \
  {                                                                        \
    bf16x8 af[2];                                                          \
    _Pragma("unroll")                                                      \
    for (int rt = 0; rt < 2; ++rt)                                         \
      af[rt] = *(const bf16x8*)&Xa[(rp * 32 + rt * 16 + m) * XROW +        \
                                   (s_) * 32 + q * 8];                     \
    _Pragma("unroll")                                                      \
    for (int c6 = 0; c6 < 6; ++c6)                                         \
      _Pragma("unroll")                                                    \
      for (int rt = 0; rt < 2; ++rt)                                       \
        acc[rt][c6] = __builtin_amdgcn_mfma_f32_16x16x32_bf16(             \
            af[rt], arr[c6], acc[rt][c6], 0, 0, 0);                        \
  }

__global__ __launch_bounds__(512, 4) void gcn_main_mfma(
    const float* __restrict__ x,
    const float* __restrict__ ws,
    float* __restrict__ out) {
  __shared__ __align__(16) uint16_t Xa[TTW * XROW];  // 50176 B

  const int tid = threadIdx.x;
  const int h  = blockIdx.x;            // h pinned to XCD (bid%8 == h)
  const int t0 = blockIdx.y * TTW;
  const int n  = blockIdx.z;

  const int wave = tid >> 6, lane = tid & 63;
  const int rp = wave >> 2, cs = wave & 3;   // row-half, col-sextet
  const int m = lane & 15, q = lane >> 4;

  const uint16_t* mb = (const uint16_t*)(ws + WS_MB) +
                       ((size_t)h * NSTEP * NCT + cs * 6) * 512 + lane * 8;

  // prologue: issue first pair of B-step loads; latency hides under x staging
  bf16x8 bA[6], bB[6], bC[6], bD[6];
  LOADB(bA, 0);
  LOADB(bB, 1);

  for (int u = tid; u < CG * TTW * 6; u += 512) {
    int c = u / (TTW * 6);
    int r = u % (TTW * 6);
    int tt = r / 6, vc = r % 6;
    const float* xrow =
        x + ((size_t)((n * CIN + h * CG + c) * TDIM) + (t0 + tt)) * V;
    float f0 = xrow[vc * 4 + 0];
    float f1 = xrow[vc * 4 + 1];
    float f2 = xrow[vc * 4 + 2];
    float f3 = (vc < 5) ? xrow[vc * 4 + 3] : 0.f;
    uint32_t lo = f2bf_rne(f0) | (f2bf_rne(f1) << 16);
    uint32_t hi = f2bf_rne(f2) | (f2bf_rne(f3) << 16);
    *(uint2*)&Xa[tt * XROW + c * VP + vc * 4] = make_uint2(lo, hi);
  }
  __syncthreads();

  f32x4 acc[2][6];
#pragma unroll
  for (int rt = 0; rt < 2; ++rt)
#pragma unroll
    for (int c6 = 0; c6 < 6; ++c6) acc[rt][c6] = (f32x4){0.f, 0.f, 0.f, 0.f};

  // 12 steps, fully unrolled, pair ping-pong register pipeline.
  LOADB(bC, 2);
  LOADB(bD, 3);
  STEPB(bA, 0);
  STEPB(bB, 1);
  LOADB(bA, 4);
  LOADB(bB, 5);
  STEPB(bC, 2);
  STEPB(bD, 3);
  LOADB(bC, 6);
  LOADB(bD, 7);
  STEPB(bA, 4);
  STEPB(bB, 5);
  LOADB(bA, 8);
  LOADB(bB, 9);
  STEPB(bC, 6);
  STEPB(bD, 7);
  LOADB(bC, 10);
  LOADB(bD, 11);
  STEPB(bA, 8);
  STEPB(bB, 9);
  STEPB(bC, 10);
  STEPB(bD, 11);

#pragma unroll
  for (int c6 = 0; c6 < 6; ++c6) {
    int col = (cs * 6 + c6) * 16 + m;
    int o = col / VP, w = col - o * VP;
    float sc = ws[WS_SCALE + h * CG + o];
    float of = ws[WS_OFFS + h * CG + o];
    bool valid = (w < V);
    float* obase =
        out + ((size_t)(n * OUTC + h * CG + o) * TDIM + t0) * V + w;
#pragma unroll
    for (int rt = 0; rt < 2; ++rt) {
#pragma unroll
      for (int reg = 0; reg < 4; ++reg) {
        int row = rp * 32 + rt * 16 + q * 4 + reg;
        float resid = bf2f(Xa[row * XROW + col]);
        float y = fmaf(acc[rt][c6][reg], sc, of) + resid;
        if (valid) obase[(size_t)row * V] = fmaxf(y, 0.f);
      }
    }
  }
}

// ---------------- fallback VALU main (81 KB ws, round-2 proven) ----------------
__global__ __launch_bounds__(256, 3) void gcn_main_valu(
    const float* __restrict__ x,
    const float* __restrict__ ws,
    float* __restrict__ out) {
  __shared__ __align__(16) uint16_t Xs[CG * TT * VP];

  const int tid = threadIdx.x;
  const int t0 = blockIdx.x * TT;
  const int h  = blockIdx.y;
  const int n  = blockIdx.z;

  for (int u = tid; u < CG * TT * 6; u += 256) {
    int c = u / (TT * 6);
    int r = u % (TT * 6);
    int tt = r / 6, vc = r % 6;
    const float* xrow =
        x + ((size_t)((n * CIN + h * CG + c) * TDIM) + (t0 + tt)) * V;
    float f0 = xrow[vc * 4 + 0];
    float f1 = xrow[vc * 4 + 1];
    float f2 = xrow[vc * 4 + 2];
    float f3 = (vc < 5) ? xrow[vc * 4 + 3] : 0.f;
    uint32_t lo = f2bf_rne(f0) | (f2bf_rne(f1) << 16);
    uint32_t hi = f2bf_rne(f2) | (f2bf_rne(f3) << 16);
    *(uint2*)&Xs[(c * TT + tt) * VP + vc * 4] = make_uint2(lo, hi);
  }
  __syncthreads();

  const int oq = __builtin_amdgcn_readfirstlane(tid >> 6);
  const int tt = tid & 63;

  const float* wt  = ws + WS_WT  + ((size_t)h * CG * CG);
  const float* bna = ws + WS_BNA + ((size_t)h * VP * VP);

  float acc[4][VP];
#pragma unroll
  for (int o = 0; o < 4; ++o)
#pragma unroll
    for (int w = 0; w < VP; ++w) acc[o][w] = 0.f;

  for (int k = 0; k < KK; ++k) {
    const float* wtk  = wt  + (size_t)k * H * CG * CG;
    const float* bnak = bna + (size_t)k * H * VP * VP;
    for (int vb = 0; vb < 3; ++vb) {
      float xwv[4][8];
#pragma unroll
      for (int o = 0; o < 4; ++o)
#pragma unroll
        for (int j = 0; j < 8; ++j) xwv[o][j] = 0.f;
#pragma unroll 4
      for (int c = 0; c < CG; ++c) {
        uint4 raw = *(const uint4*)&Xs[(c * TT + tt) * VP + vb * 8];
        float4 wv = *(const float4*)&wtk[c * CG + (oq << 2)];
        float xv[8];
        xv[0] = __uint_as_float(raw.x << 16);
        xv[1] = __uint_as_float(raw.x & 0xffff0000u);
        xv[2] = __uint_as_float(raw.y << 16);
        xv[3] = __uint_as_float(raw.y & 0xffff0000u);
        xv[4] = __uint_as_float(raw.z << 16);
        xv[5] = __uint_as_float(raw.z & 0xffff0000u);
        xv[6] = __uint_as_float(raw.w << 16);
        xv[7] = __uint_as_float(raw.w & 0xffff0000u);
#pragma unroll
        for (int o = 0; o < 4; ++o) {
          float wo = (&wv.x)[o];
#pragma unroll
          for (int j = 0; j < 8; ++j) xwv[o][j] = fmaf(wo, xv[j], xwv[o][j]);
        }
      }
#pragma unroll
      for (int j = 0; j < 8; ++j) {
        const int v = vb * 8 + j;
        const float* bnrow = &bnak[v * VP];
#pragma unroll
        for (int wb = 0; wb < 6; ++wb) {
          float4 bn = *(const float4*)(bnrow + wb * 4);
#pragma unroll
          for (int o = 0; o < 4; ++o) {
            acc[o][wb * 4 + 0] = fmaf(xwv[o][j], bn.x, acc[o][wb * 4 + 0]);
            acc[o][wb * 4 + 1] = fmaf(xwv[o][j], bn.y, acc[o][wb * 4 + 1]);
            acc[o][wb * 4 + 2] = fmaf(xwv[o][j], bn.z, acc[o][wb * 4 + 2]);
            acc[o][wb * 4 + 3] = fmaf(xwv[o][j], bn.w, acc[o][wb * 4 + 3]);
          }
        }
      }
    }
  }

#pragma unroll
  for (int o = 0; o < 4; ++o) {
    int og = (oq << 2) + o;
    int oc = h * CG + og;
    float sc = ws[WS_SCALE + oc];
    float of = ws[WS_OFFS + oc];
    float* orow = out + ((size_t)(n * OUTC + oc) * TDIM + (t0 + tt)) * V;
    const uint16_t* xsrow = &Xs[(og * TT + tt) * VP];
#pragma unroll
    for (int w = 0; w < V; ++w) {
      float resid = bf2f(xsrow[w]);
      float y = fmaf(acc[o][w], sc, of) + resid;
      orow[w] = fmaxf(y, 0.f);
    }
  }
}

extern "C" void kernel_launch(void* const* d_in, const int* in_sizes, int n_in,
                              void* d_out, int out_size, void* d_ws, size_t ws_size,
                              hipStream_t stream) {
  const float* x      = (const float*)d_in[0];
  const float* emb    = (const float*)d_in[1];
  const float* A      = (const float*)d_in[2];
  const float* conv_w = (const float*)d_in[3];
  const float* conv_b = (const float*)d_in[4];
  const float* gamma  = (const float*)d_in[5];
  const float* beta   = (const float*)d_in[6];
  const float* mean   = (const float*)d_in[7];
  const float* var    = (const float*)d_in[8];
  const int*   hop    = (const int*)d_in[9];
  float* ws  = (float*)d_ws;
  float* out = (float*)d_out;

  int n_hop = in_sizes[1] / (KK * H);

  if (ws_size >= WS_NEED_BYTES) {
    prep_fused<<<dim3(H, NSTEP), dim3(256), 0, stream>>>(
        emb, A, conv_w, conv_b, gamma, beta, mean, var, hop, n_hop, ws);
    gcn_main_mfma<<<dim3(H, TDIM / TTW, NB), dim3(512), 0, stream>>>(x, ws, out);
  } else {
    prep1_kernel<<<dim3(KK * H + 1 + 24), dim3(256), 0, stream>>>(
        emb, A, conv_w, conv_b, gamma, beta, mean, var, hop, n_hop, ws);
    gcn_main_valu<<<dim3(TDIM / TT, H, NB), dim3(256), 0, stream>>>(x, ws, out);
  }
}